// Round 5
// baseline (151.639 us; speedup 1.0000x reference)
//
#include <hip/hip_runtime.h>

// FocalSelfAttention on MI355X. fp32 I/O, bf16 MFMA compute, fp32 accum.
// B=4, C=128, H=W=48, WS=4 -> 144 windows/batch, 16 q/window, NH=8, hd=16,
// Nkv = 64 local + 720 pooled.
//
// v13 (resubmit; round-4 failure was container acquisition, kernel never ran):
//  * attn: barrier-free pooled loop. v12 showed dur invariant to 2x waves
//    and 6x less HBM -> correlated per-tile vmcnt(0)+barrier stall (m233)
//    across phase-aligned blocks. K/V fragments now gathered per-wave from
//    L2 (KVg 188KB/batch is L2-resident), plain unrolled loads (NO manual
//    double-buffer structs -- that spilled in v11). LDS 52.2 -> 21.8 KB,
//    zero barriers in the main loop, one before out-proj.
//  * k_gemm_kv: pooling fused in (reads token-major Xt, fully coalesced,
//    replaces Pml + prep's pool section); V mid-range output transposed
//    through LDS -> coalesced v8s stores (was 2-B scatter).
//  * k_prep: transpose + LN stats + weight conversion only (304 blocks).

typedef unsigned short u16;
typedef short v8s __attribute__((ext_vector_type(8)));
typedef v8s __attribute__((may_alias)) v8s_am;
typedef short v4s __attribute__((ext_vector_type(4)));
typedef v4s __attribute__((may_alias)) v4s_am;
typedef float v4f __attribute__((ext_vector_type(4)));

#define MFMA_BF16(a, b, c) __builtin_amdgcn_mfma_f32_16x16x32_bf16(a, b, c, 0, 0, 0)

#if __has_builtin(__builtin_amdgcn_mfma_f32_16x16x16bf16_1k)
#define MFMA16(a, b, c) __builtin_amdgcn_mfma_f32_16x16x16bf16_1k(a, b, c, 0, 0, 0)
#else
static __device__ __forceinline__ v4f mfma16_fb(v4s a, v4s b, v4f c) {
    v8s a8 = {a[0], a[1], a[2], a[3], 0, 0, 0, 0};
    v8s b8 = {b[0], b[1], b[2], b[3], 0, 0, 0, 0};
    return MFMA_BF16(a8, b8, c);
}
#define MFMA16(a, b, c) mfma16_fb(a, b, c)
#endif

#if __has_builtin(__builtin_amdgcn_exp2f)
#define EXP2(x) __builtin_amdgcn_exp2f(x)
#else
#define EXP2(x) exp2f(x)
#endif

__device__ __forceinline__ float b2f(u16 u) {
    union { unsigned int i; float f; } x;
    x.i = ((unsigned int)u) << 16;
    return x.f;
}
__device__ __forceinline__ u16 f2b(float f) {
    union { float f; unsigned int i; } x;
    x.f = f;
    unsigned int u = x.i;
    return (u16)((u + 0x7fffu + ((u >> 16) & 1u)) >> 16);
}

// ---------------------------------------------------------------------------
// Kernel 1: blocks 0..287: transpose fp32 NCHW -> bf16 token-major
// Xt[9216][128] (32 px/block) + per-pixel LN stats (mu, rstd) -> MuRs.
// Blocks 288..303: weights fp32->bf16 into Wb; block 288 also ln params.
__global__ __launch_bounds__(256) void k_prep(
    const float* __restrict__ F,
    const float* __restrict__ qw, const float* __restrict__ kvw,
    const float* __restrict__ ow,
    const float* __restrict__ lnw, const float* __restrict__ lnb,
    u16* __restrict__ Xt, u16* __restrict__ Wb, float* __restrict__ MuRs)
{
    int blk = blockIdx.x;
    int t = threadIdx.x;
    if (blk >= 288) {   // weight conversion: 16 blocks x 256 thr x 16 f32
        int base = (blk - 288) * 4096 + t * 16;
#pragma unroll
        for (int i = 0; i < 4; ++i) {
            int idx = base + i * 4;
            const float* src; int off;
            if (idx < 16384)      { src = qw;  off = idx; }
            else if (idx < 49152) { src = kvw; off = idx - 16384; }
            else                  { src = ow;  off = idx - 49152; }
            float4 v = *(const float4*)(src + off);
            unsigned long long packed =
                (unsigned long long)f2b(v.x) |
                ((unsigned long long)f2b(v.y) << 16) |
                ((unsigned long long)f2b(v.z) << 32) |
                ((unsigned long long)f2b(v.w) << 48);
            *(unsigned long long*)(Wb + idx) = packed;
        }
        if (blk == 288) {   // ln params -> bf16 at Wb+65536
            Wb[65536 + t] = f2b(t < 128 ? lnw[t] : lnb[t - 128]);
        }
        return;
    }
    __shared__ u16 X[128][34];
    int b = blk / 72;
    int p0 = (blk % 72) * 32;
#pragma unroll 4
    for (int i = 0; i < 16; ++i) {
        int c = i * 8 + (t >> 5);
        int pix = t & 31;
        X[c][pix] = f2b(F[((size_t)(b * 128 + c)) * 2304 + p0 + pix]);
    }
    __syncthreads();
    int pix = t >> 3;
    int c0 = (t & 7) * 16;
    size_t row = (size_t)(b * 2304 + p0 + pix) * 128;
    float s = 0.f, s2 = 0.f;
#pragma unroll
    for (int sg = 0; sg < 2; ++sg) {
        v8s raw;
#pragma unroll
        for (int j = 0; j < 8; ++j) {
            u16 u = X[c0 + sg * 8 + j][pix];
            raw[j] = (short)u;
            float v = b2f(u);
            s += v; s2 += v * v;
        }
        *(v8s_am*)&Xt[row + c0 + sg * 8] = raw;
    }
    // 8 consecutive lanes own one pixel
    s += __shfl_xor(s, 1);  s2 += __shfl_xor(s2, 1);
    s += __shfl_xor(s, 2);  s2 += __shfl_xor(s2, 2);
    s += __shfl_xor(s, 4);  s2 += __shfl_xor(s2, 4);
    if ((t & 7) == 0) {
        float mean = s * (1.f / 128.f);
        float var = s2 * (1.f / 128.f) - mean * mean;
        float rstd = rsqrtf(var + 1e-5f);
        MuRs[(b * 2304 + p0 + pix) * 2]     = mean;
        MuRs[(b * 2304 + p0 + pix) * 2 + 1] = rstd;
    }
}

// ---------------------------------------------------------------------------
// Kernel 2: pooled-token K/V projection. Pooling is fused: each block builds
// its 64 pooled tokens (tm..tm+63) from token-major Xt (coalesced 64B reads)
// directly into LDS Al, then GEMMs vs the kv weights.
// K -> KVg[2880][128] token-major; V -> VTg[b][128 ch][720 tok] transposed
// (mid range via LDS-transposed coalesced stores; glo keeps scatter).
__global__ __launch_bounds__(256) void k_gemm_kv(
    const u16* __restrict__ Xt,
    const u16* __restrict__ W,
    const float* __restrict__ bias,
    u16* __restrict__ KVg,
    u16* __restrict__ VTg)
{
    __shared__ u16 Al[64][136];
    __shared__ u16 Wl[64][136];
    int tm = blockIdx.x * 64, tn = blockIdx.y * 64;
    int t = threadIdx.x;
    // --- weight tile load ---
    {
        int seg = t & 15, r0 = t >> 4;
#pragma unroll
        for (int i = 0; i < 4; ++i) {
            int r = r0 + 16 * i;
            *(v8s_am*)&Wl[r][seg * 8] = *(const v8s_am*)&W[((size_t)(tn + r)) * 128 + seg * 8];
        }
    }
    // --- fused pooling: token (tm+r), channels cp..cp+31, from Xt ---
    {
        int r = t >> 2;              // token slot 0..63
        int cp = (t & 3) * 32;       // channel part
        int m = tm + r;
        float s[32];
#pragma unroll
        for (int j = 0; j < 32; ++j) s[j] = 0.f;
        if (m < 2304) {              // mid: avg 2x2 pixels
            int b = m / 576, loc = m % 576;
            int i = loc / 24, j = loc % 24;
            int base = b * 2304 + (2 * i) * 48 + 2 * j;
#pragma unroll
            for (int rr = 0; rr < 4; ++rr) {
                int row = base + (rr >> 1) * 48 + (rr & 1);
#pragma unroll
                for (int k = 0; k < 4; ++k) {
                    v8s x = *(const v8s_am*)&Xt[(size_t)row * 128 + cp + k * 8];
#pragma unroll
                    for (int jj = 0; jj < 8; ++jj) s[k * 8 + jj] += b2f((u16)x[jj]);
                }
            }
#pragma unroll
            for (int k = 0; k < 4; ++k) {
                v8s o;
#pragma unroll
                for (int jj = 0; jj < 8; ++jj) o[jj] = (short)f2b(s[k * 8 + jj] * 0.25f);
                *(v8s_am*)&Al[r][cp + k * 8] = o;
            }
        } else {                     // glo: avg 4x4 pixels
            int r2 = m - 2304;
            int b = r2 / 144, loc = r2 % 144;
            int i = loc / 12, j = loc % 12;
            int base = b * 2304 + (4 * i) * 48 + 4 * j;
#pragma unroll
            for (int rr = 0; rr < 16; ++rr) {
                int row = base + (rr >> 2) * 48 + (rr & 3);
#pragma unroll
                for (int k = 0; k < 4; ++k) {
                    v8s x = *(const v8s_am*)&Xt[(size_t)row * 128 + cp + k * 8];
#pragma unroll
                    for (int jj = 0; jj < 8; ++jj) s[k * 8 + jj] += b2f((u16)x[jj]);
                }
            }
#pragma unroll
            for (int k = 0; k < 4; ++k) {
                v8s o;
#pragma unroll
                for (int jj = 0; jj < 8; ++jj) o[jj] = (short)f2b(s[k * 8 + jj] * 0.0625f);
                *(v8s_am*)&Al[r][cp + k * 8] = o;
            }
        }
    }
    __syncthreads();
    int lane = t & 63, wave = t >> 6;
    int n15 = lane & 15, quad = lane >> 4;
    int wm = (wave & 1) * 32, wn = (wave >> 1) * 32;
    v4f acc[2][2] = {};
#pragma unroll
    for (int kc = 0; kc < 4; ++kc) {
        v8s a[2], bb[2];
#pragma unroll
        for (int im = 0; im < 2; ++im)
            a[im] = *(const v8s_am*)&Al[wm + im * 16 + n15][kc * 32 + quad * 8];
#pragma unroll
        for (int in = 0; in < 2; ++in)
            bb[in] = *(const v8s_am*)&Wl[wn + in * 16 + n15][kc * 32 + quad * 8];
#pragma unroll
        for (int im = 0; im < 2; ++im)
#pragma unroll
            for (int in = 0; in < 2; ++in)
                acc[im][in] = MFMA_BF16(a[im], bb[in], acc[im][in]);
    }
    bool vblk = (tn >= 128);
    bool vfast = vblk && (tm < 2304);        // block-uniform
    u16* vt = &Al[0][0];                     // overlay [64 ch][72 tok]
    if (vfast) __syncthreads();              // Al reads done before overlay
#pragma unroll
    for (int in = 0; in < 2; ++in) {
        int n = tn + wn + in * 16 + n15;
        float bv = bias[n];
#pragma unroll
        for (int im = 0; im < 2; ++im) {
            int mbase = tm + wm + im * 16 + quad * 4;
#pragma unroll
            for (int r = 0; r < 4; ++r) {
                int m = mbase + r;
                u16 h = f2b(acc[im][in][r] + bv);
                if (!vblk) {
                    KVg[((size_t)m) * 128 + n] = h;
                } else if (vfast) {
                    vt[(n - tn) * 72 + (wm + im * 16 + quad * 4 + r)] = h;
                } else {
                    int ch = n - 128, bb2, tok;
                    int r2 = m - 2304; bb2 = r2 / 144; tok = 576 + r2 % 144;
                    VTg[((size_t)(bb2 * 128 + ch)) * 720 + tok] = h;
                }
            }
        }
    }
    if (vfast) {
        __syncthreads();
        int ch = t >> 2, seg = t & 3;
        int b = tm / 576, tokbase = tm % 576;
        v8s a0 = *(const v8s_am*)&vt[ch * 72 + seg * 16];
        v8s a1 = *(const v8s_am*)&vt[ch * 72 + seg * 16 + 8];
        size_t d = ((size_t)(b * 128 + (tn - 128) + ch)) * 720 + tokbase + seg * 16;
        *(v8s_am*)&VTg[d]     = a0;
        *(v8s_am*)&VTg[d + 8] = a1;
    }
}

// ---------------------------------------------------------------------------
// Kernel 3: fused per-window attention. 576 blocks x 512 thr (8 waves),
// wave w = head w. Barrier-free main loop: K/V fragments gathered from L2
// per wave (no LDS staging, no per-tile barriers). LDS 21.8 KB.
__device__ __forceinline__ int rbase_of(int b, int tb) {
    return (tb < 9) ? (b * 576 + tb * 64) : (2304 + b * 144 + (tb - 9) * 64);
}

__global__ __launch_bounds__(512, 4) void k_attn_fused(
    const float* __restrict__ F,
    const u16* __restrict__ Xt,
    const float* __restrict__ MuRs,
    const u16* __restrict__ KVg,
    const u16* __restrict__ VTg,
    const u16* __restrict__ Wb,     // [qwb|kvwb|owb|lnwb|lnbb]
    const float* __restrict__ qb,
    const float* __restrict__ kvb,
    const float* __restrict__ ob,
    float* __restrict__ Out)
{
    __shared__ u16 VtW[8][16][68];   // per-wave local V^T (wave-private)
    __shared__ u16 At[16][136];      // attended tokens for out-proj

    const u16* qwb  = Wb;
    const u16* kvwb = Wb + 16384;
    const u16* owb  = Wb + 49152;
    const u16* lnwb = Wb + 65536;
    const u16* lnbb = Wb + 65664;

    // Bijective XCD swizzle: xcd = blk&7 -> one batch-half per XCD.
    int blk = blockIdx.x;
    int xcd = blk & 7, jj = blk >> 3;       // jj in 0..71
    int b = xcd >> 1;
    int wr = (xcd & 1) * 6 + jj / 12;
    int wc = jj % 12;

    int t = threadIdx.x;
    int lane = t & 63, wave = t >> 6, n15 = lane & 15, quad = lane >> 4;
    v8s zf8 = {};
    v4f zz4 = {0.f, 0.f, 0.f, 0.f};
    const float QSCALE = 0.25f * 1.44269504f;

    // --- per-lane LN'd window token B-fragments (tok = n15) ---
    int qh = wr * 4 + (n15 >> 2), qw_ = wc * 4 + (n15 & 3);
    int qpix = b * 2304 + qh * 48 + qw_;
    float mu = MuRs[qpix * 2], rstd = MuRs[qpix * 2 + 1];
    v8s xln[4];
#pragma unroll
    for (int kc = 0; kc < 4; ++kc) {
        v8s x  = *(const v8s_am*)&Xt[(size_t)qpix * 128 + kc * 32 + quad * 8];
        v8s lw = *(const v8s_am*)&lnwb[kc * 32 + quad * 8];
        v8s lb = *(const v8s_am*)&lnbb[kc * 32 + quad * 8];
        v8s y;
#pragma unroll
        for (int j = 0; j < 8; ++j)
            y[j] = (short)f2b((b2f((u16)x[j]) - mu) * rstd * b2f((u16)lw[j]) + b2f((u16)lb[j]));
        xln[kc] = y;
    }

    // --- Q projection TRANSPOSED for head=wave: D[d=quad*4+r][q=n15] ---
    v4s qf;
    {
        int n0 = wave * 16;
        v4f qacc = zz4;
#pragma unroll
        for (int kc = 0; kc < 4; ++kc) {
            v8s aw = *(const v8s_am*)&qwb[((size_t)(n0 + n15)) * 128 + kc * 32 + quad * 8];
            qacc = MFMA_BF16(aw, xln[kc], qacc);
        }
#pragma unroll
        for (int r = 0; r < 4; ++r)
            qf[r] = (short)f2b((qacc[r] + qb[n0 + quad * 4 + r]) * QSCALE);
    }

    // --- local K/V projection TRANSPOSED (this wave's head only) ---
    v4s kfloc[4];
#pragma unroll
    for (int g = 0; g < 4; ++g) {
        int tl = g * 16 + n15;
        int fh = tl >> 3, fw = tl & 7;
        int hh = wr * 4 - 2 + fh, ww = wc * 4 - 2 + fw;
        bool valid = (hh >= 0 && hh < 48 && ww >= 0 && ww < 48);
        size_t arow = (size_t)(b * 2304 + hh * 48 + ww) * 128;
        v8s xb[4];
#pragma unroll
        for (int kc = 0; kc < 4; ++kc) {
            v8s v = zf8;
            if (valid) v = *(const v8s_am*)&Xt[arow + kc * 32 + quad * 8];
            xb[kc] = v;
        }
#pragma unroll
        for (int s = 0; s < 2; ++s) {    // s=0: K strip, s=1: V strip
            int sbase = s * 128 + wave * 16;
            v4f acc = zz4;
#pragma unroll
            for (int kc = 0; kc < 4; ++kc) {
                v8s aw = *(const v8s_am*)&kvwb[((size_t)(sbase + n15)) * 128 + kc * 32 + quad * 8];
                acc = MFMA_BF16(aw, xb[kc], acc);
            }
            if (s == 0) {
                v4s k4;
#pragma unroll
                for (int r = 0; r < 4; ++r)
                    k4[r] = (short)f2b(acc[r] + kvb[sbase + quad * 4 + r]);
                kfloc[g] = k4;
            } else {
#pragma unroll
                for (int r = 0; r < 4; ++r)
                    VtW[wave][quad * 4 + r][g * 16 + n15] =
                        f2b(acc[r] + kvb[sbase + quad * 4 + r]);
            }
        }
    }

    v4f oacc = zz4;
    float ls = 0.f;

    // --- local chunk (K frags in regs, V from wave-private LDS slice) ---
    asm volatile("s_waitcnt lgkmcnt(0)" ::: "memory");
    __builtin_amdgcn_sched_barrier(0);
#pragma unroll
    for (int g = 0; g < 4; ++g) {
        v4f St = MFMA16(kfloc[g], qf, zz4);     // S^T[tok=quad*4+r][q=n15]
        float p0 = EXP2(St[0]), p1 = EXP2(St[1]);
        float p2 = EXP2(St[2]), p3 = EXP2(St[3]);
        ls += (p0 + p1) + (p2 + p3);
        v4s pk = {(short)f2b(p0), (short)f2b(p1), (short)f2b(p2), (short)f2b(p3)};
        v4s vf = *(const v4s_am*)&VtW[wave][n15][g * 16 + quad * 4];
        oacc = MFMA16(vf, pk, oacc);            // O^T[ch=quad*4+r][q=n15]
    }

    // --- pooled tiles 0..10: barrier-free, direct-from-L2 fragments.
    //     Fully unrolled so the compiler pipelines loads across tiles. ---
    const u16* kcol  = KVg + wave * 16 + quad * 4;
    const u16* vrow0 = VTg + (size_t)b * 92160 + (size_t)(wave * 16 + n15) * 720 + quad * 4;
#pragma unroll
    for (int tb = 0; tb < 11; ++tb) {
        int rbase = rbase_of(b, tb);
        v4s kf[4], vp[4];
#pragma unroll
        for (int g = 0; g < 4; ++g) {
            kf[g] = *(const v4s_am*)(kcol + (size_t)(rbase + g * 16 + n15) * 128);
            vp[g] = *(const v4s_am*)(vrow0 + tb * 64 + g * 16);
        }
#pragma unroll
        for (int g = 0; g < 4; ++g) {
            v4f St = MFMA16(kf[g], qf, zz4);
            float p0 = EXP2(St[0]), p1 = EXP2(St[1]);
            float p2 = EXP2(St[2]), p3 = EXP2(St[3]);
            ls += (p0 + p1) + (p2 + p3);
            v4s pk = {(short)f2b(p0), (short)f2b(p1), (short)f2b(p2), (short)f2b(p3)};
            oacc = MFMA16(vp[g], pk, oacc);
        }
    }
    // --- tile 11: 16 toks (glo 128..143) ---
    {
        int rbase = 2304 + b * 144 + 128;
        v4s kf = *(const v4s_am*)(kcol + (size_t)(rbase + n15) * 128);
        v4s vf = *(const v4s_am*)(vrow0 + 704);
        v4f St = MFMA16(kf, qf, zz4);
        float p0 = EXP2(St[0]), p1 = EXP2(St[1]);
        float p2 = EXP2(St[2]), p3 = EXP2(St[3]);
        ls += (p0 + p1) + (p2 + p3);
        v4s pk = {(short)f2b(p0), (short)f2b(p1), (short)f2b(p2), (short)f2b(p3)};
        oacc = MFMA16(vf, pk, oacc);
    }

    // --- l reduce (across quads); write attended into At ---
    ls += __shfl_xor(ls, 16);
    ls += __shfl_xor(ls, 32);
    {
        float inv = 1.f / ls;
        v4s a4 = {(short)f2b(oacc[0] * inv), (short)f2b(oacc[1] * inv),
                  (short)f2b(oacc[2] * inv), (short)f2b(oacc[3] * inv)};
        *(v4s_am*)&At[n15][wave * 16 + quad * 4] = a4;
    }
    __syncthreads();    // the only block-wide barrier in this kernel

    // --- out projection (16 out-ch per wave) + bias + residual, NCHW ---
    {
        int n0 = wave * 16;
        v4f oa = zz4;
#pragma unroll
        for (int kc = 0; kc < 4; ++kc) {
            v8s af = *(const v8s_am*)&At[n15][kc * 32 + quad * 8];
            v8s bf = *(const v8s_am*)&owb[((size_t)(n0 + n15)) * 128 + kc * 32 + quad * 8];
            oa = MFMA_BF16(af, bf, oa);
        }
        int c = n0 + n15;
        float bv = ob[c];
#pragma unroll
        for (int r = 0; r < 4; ++r) {
            int pix = quad * 4 + r;
            int hh = wr * 4 + (pix >> 2), ww_ = wc * 4 + (pix & 3);
            size_t idx = ((size_t)(b * 128 + c)) * 2304 + hh * 48 + ww_;
            Out[idx] = oa[r] + bv + F[idx];
        }
    }
}

// ---------------------------------------------------------------------------
extern "C" void kernel_launch(void* const* d_in, const int* in_sizes, int n_in,
                              void* d_out, int out_size, void* d_ws, size_t ws_size,
                              hipStream_t stream)
{
    const float* F   = (const float*)d_in[0];
    const float* lnw = (const float*)d_in[1];
    const float* lnb = (const float*)d_in[2];
    const float* qw  = (const float*)d_in[3];
    const float* qb  = (const float*)d_in[4];
    const float* kvw = (const float*)d_in[5];
    const float* kvb = (const float*)d_in[6];
    const float* ow  = (const float*)d_in[7];
    const float* ob  = (const float*)d_in[8];
    float* Out = (float*)d_out;

    u16* ws    = (u16*)d_ws;
    u16* Xt    = ws;                    // 9216*128  = 1,179,648 u16
    u16* Pml   = Xt + 9216 * 128;       // (unused in v13; layout kept)
    u16* KVg   = Pml + 2880 * 128;      // 2880*128  =   368,640
    u16* VTg   = KVg + 2880 * 128;      // 4*128*720 =   368,640
    u16* Wb    = VTg + 4 * 128 * 720;   // 65,792 [qwb|kvwb|owb|lnwb|lnbb]
    float* MuRs = (float*)(Wb + 65792); // 9216*2 fp32
    // total: ~4.77 MiB
    u16* kvwb = Wb + 16384;

    k_prep<<<304, 256, 0, stream>>>(F, qw, kvw, ow, lnw, lnb, Xt, Wb, MuRs);
    k_gemm_kv<<<dim3(45, 4), 256, 0, stream>>>(Xt, kvwb, kvb, KVg, VTg);
    k_attn_fused<<<576, 512, 0, stream>>>(F, Xt, MuRs, KVg, VTg, Wb,
                                          qb, kvb, ob, Out);
}

// Round 6
// 139.647 us; speedup vs baseline: 1.0859x; 1.0859x over previous
//
#include <hip/hip_runtime.h>

// FocalSelfAttention on MI355X. fp32 I/O, bf16 MFMA compute, fp32 accum.
// B=4, C=128, H=W=48, WS=4 -> 144 windows/batch, 16 q/window, NH=8, hd=16,
// Nkv = 64 local + 720 pooled.
//
// v14:
//  * attn: 2 windows per block (288 blocks x 512 thr, 8 waves; wave = head
//    for BOTH windows). v12's staged-KB structure kept (v13's direct L2
//    gather regressed 56->70 us). Per-tile staged K + V fragment loads are
//    shared between the two windows -> the per-tile stall round serves 32
//    queries instead of 16. LDS 69.6 KB -> 2 blocks/CU.
//  * prep + gemm_kv merged into ONE dispatch (484 blocks): gemm blocks pool
//    directly from fp32 F (v12 k_pool math) and convert their kv-weight
//    tile from fp32 inline -> no dependency on prep output, one less
//    dispatch round. (Non-attn time was ~78 us across 3 structures -- the
//    dispatch count, not the kernel content, is the cost.)

typedef unsigned short u16;
typedef short v8s __attribute__((ext_vector_type(8)));
typedef v8s __attribute__((may_alias)) v8s_am;
typedef short v4s __attribute__((ext_vector_type(4)));
typedef v4s __attribute__((may_alias)) v4s_am;
typedef float v4f __attribute__((ext_vector_type(4)));

#define MFMA_BF16(a, b, c) __builtin_amdgcn_mfma_f32_16x16x32_bf16(a, b, c, 0, 0, 0)

#if __has_builtin(__builtin_amdgcn_mfma_f32_16x16x16bf16_1k)
#define MFMA16(a, b, c) __builtin_amdgcn_mfma_f32_16x16x16bf16_1k(a, b, c, 0, 0, 0)
#else
static __device__ __forceinline__ v4f mfma16_fb(v4s a, v4s b, v4f c) {
    v8s a8 = {a[0], a[1], a[2], a[3], 0, 0, 0, 0};
    v8s b8 = {b[0], b[1], b[2], b[3], 0, 0, 0, 0};
    return MFMA_BF16(a8, b8, c);
}
#define MFMA16(a, b, c) mfma16_fb(a, b, c)
#endif

#if __has_builtin(__builtin_amdgcn_exp2f)
#define EXP2(x) __builtin_amdgcn_exp2f(x)
#else
#define EXP2(x) exp2f(x)
#endif

__device__ __forceinline__ float b2f(u16 u) {
    union { unsigned int i; float f; } x;
    x.i = ((unsigned int)u) << 16;
    return x.f;
}
__device__ __forceinline__ u16 f2b(float f) {
    union { float f; unsigned int i; } x;
    x.f = f;
    unsigned int u = x.i;
    return (u16)((u + 0x7fffu + ((u >> 16) & 1u)) >> 16);
}

// ---------------------------------------------------------------------------
// Kernel 1 (merged prep + pooled K/V GEMM), 484 blocks x 256:
//  [0,288):   transpose fp32 NCHW -> bf16 token-major Xt + LN stats MuRs
//  [288,304): weights fp32->bf16 into Wb (blk 288 also ln params)
//  [304,484): pooled K/V projection: pool 64 tokens from F (fp32), convert
//             kv-weight tile from fp32 inline, GEMM, write KVg / VTg.
__global__ __launch_bounds__(256) void k_prep_gemm(
    const float* __restrict__ F,
    const float* __restrict__ qw, const float* __restrict__ kvw,
    const float* __restrict__ ow,
    const float* __restrict__ lnw, const float* __restrict__ lnb,
    const float* __restrict__ kvb,
    u16* __restrict__ Xt, u16* __restrict__ Wb, float* __restrict__ MuRs,
    u16* __restrict__ KVg, u16* __restrict__ VTg)
{
    __shared__ u16 SH[17408];    // 34.8 KB, aliased per block range
    int blk = blockIdx.x;
    int t = threadIdx.x;

    if (blk >= 304) {
        // ---- pooled K/V GEMM: 180 blocks (45 tm x 4 tn) ----
        u16 (*Al)[136] = (u16(*)[136])SH;          // [64][136]
        u16 (*Wl)[136] = (u16(*)[136])(SH + 8704); // [64][136]
        int gb = blk - 304;
        int tm = (gb % 45) * 64, tn = (gb / 45) * 64;
        // weight tile from fp32 kvw, inline convert
        {
            int seg = t & 15, r0 = t >> 4;
#pragma unroll
            for (int i = 0; i < 4; ++i) {
                int r = r0 + 16 * i;
                const float* src = kvw + (size_t)(tn + r) * 128 + seg * 8;
                float4 v0 = *(const float4*)src;
                float4 v1 = *(const float4*)(src + 4);
                v8s o = {(short)f2b(v0.x), (short)f2b(v0.y), (short)f2b(v0.z), (short)f2b(v0.w),
                         (short)f2b(v1.x), (short)f2b(v1.y), (short)f2b(v1.z), (short)f2b(v1.w)};
                *(v8s_am*)&Wl[r][seg * 8] = o;
            }
        }
        // pooling from F: thread = (token slot, 32-ch group). tm is a
        // multiple of 64 and 2304%64==0 -> block is uniformly mid or glo.
        {
            int rs = t >> 2;             // token slot 0..63
            int cp = (t & 3) * 32;       // channel group
            int m = tm + rs;
            float s[32];
            if (m < 2304) {              // mid: avg 2x2
                int bb = m / 576, loc = m % 576;
                int ii = loc / 24, jj2 = loc % 24;
                const float* f0 = F + (size_t)(bb * 128 + cp) * 2304 + (2 * ii) * 48 + 2 * jj2;
#pragma unroll
                for (int cc = 0; cc < 32; ++cc) {
                    const float* src = f0 + (size_t)cc * 2304;
                    float2 a = *(const float2*)src;
                    float2 d = *(const float2*)(src + 48);
                    s[cc] = (a.x + a.y + d.x + d.y) * 0.25f;
                }
            } else {                     // glo: avg 4x4
                int r2 = m - 2304;
                int bb = r2 / 144, loc = r2 % 144;
                int ii = loc / 12, jj2 = loc % 12;
                const float* f0 = F + (size_t)(bb * 128 + cp) * 2304 + (4 * ii) * 48 + 4 * jj2;
#pragma unroll
                for (int cc = 0; cc < 32; ++cc) {
                    const float* src = f0 + (size_t)cc * 2304;
                    float ss = 0.f;
#pragma unroll
                    for (int di = 0; di < 4; ++di) {
                        float4 v = *(const float4*)(src + di * 48);
                        ss += (v.x + v.y) + (v.z + v.w);
                    }
                    s[cc] = ss * 0.0625f;
                }
            }
#pragma unroll
            for (int k = 0; k < 4; ++k) {
                v8s o;
#pragma unroll
                for (int jj = 0; jj < 8; ++jj) o[jj] = (short)f2b(s[k * 8 + jj]);
                *(v8s_am*)&Al[rs][cp + k * 8] = o;
            }
        }
        __syncthreads();
        int lane = t & 63, wave = t >> 6;
        int n15 = lane & 15, quad = lane >> 4;
        int wm = (wave & 1) * 32, wn = (wave >> 1) * 32;
        v4f acc[2][2] = {};
#pragma unroll
        for (int kc = 0; kc < 4; ++kc) {
            v8s a[2], bb[2];
#pragma unroll
            for (int im = 0; im < 2; ++im)
                a[im] = *(const v8s_am*)&Al[wm + im * 16 + n15][kc * 32 + quad * 8];
#pragma unroll
            for (int in = 0; in < 2; ++in)
                bb[in] = *(const v8s_am*)&Wl[wn + in * 16 + n15][kc * 32 + quad * 8];
#pragma unroll
            for (int im = 0; im < 2; ++im)
#pragma unroll
                for (int in = 0; in < 2; ++in)
                    acc[im][in] = MFMA_BF16(a[im], bb[in], acc[im][in]);
        }
        bool vblk = (tn >= 128);
        bool vfast = vblk && (tm < 2304);        // block-uniform
        u16* vt = &Al[0][0];                     // overlay [64 ch][72 tok]
        if (vfast) __syncthreads();              // Al reads done before overlay
#pragma unroll
        for (int in = 0; in < 2; ++in) {
            int n = tn + wn + in * 16 + n15;
            float bv = kvb[n];
#pragma unroll
            for (int im = 0; im < 2; ++im) {
                int mbase = tm + wm + im * 16 + quad * 4;
#pragma unroll
                for (int r = 0; r < 4; ++r) {
                    int m = mbase + r;
                    u16 h = f2b(acc[im][in][r] + bv);
                    if (!vblk) {
                        KVg[((size_t)m) * 128 + n] = h;
                    } else if (vfast) {
                        vt[(n - tn) * 72 + (wm + im * 16 + quad * 4 + r)] = h;
                    } else {
                        int ch = n - 128;
                        int r2 = m - 2304;
                        int bb2 = r2 / 144, tok = 576 + r2 % 144;
                        VTg[((size_t)(bb2 * 128 + ch)) * 720 + tok] = h;
                    }
                }
            }
        }
        if (vfast) {
            __syncthreads();
            int ch = t >> 2, seg = t & 3;
            int bb2 = tm / 576, tokbase = tm % 576;
            v8s a0 = *(const v8s_am*)&vt[ch * 72 + seg * 16];
            v8s a1 = *(const v8s_am*)&vt[ch * 72 + seg * 16 + 8];
            size_t d = ((size_t)(bb2 * 128 + (tn - 128) + ch)) * 720 + tokbase + seg * 16;
            *(v8s_am*)&VTg[d]     = a0;
            *(v8s_am*)&VTg[d + 8] = a1;
        }
        return;
    }
    if (blk >= 288) {   // ---- weight conversion: 16 blocks ----
        int base = (blk - 288) * 4096 + t * 16;
#pragma unroll
        for (int i = 0; i < 4; ++i) {
            int idx = base + i * 4;
            const float* src; int off;
            if (idx < 16384)      { src = qw;  off = idx; }
            else if (idx < 49152) { src = kvw; off = idx - 16384; }
            else                  { src = ow;  off = idx - 49152; }
            float4 v = *(const float4*)(src + off);
            unsigned long long packed =
                (unsigned long long)f2b(v.x) |
                ((unsigned long long)f2b(v.y) << 16) |
                ((unsigned long long)f2b(v.z) << 32) |
                ((unsigned long long)f2b(v.w) << 48);
            *(unsigned long long*)(Wb + idx) = packed;
        }
        if (blk == 288) {   // ln params -> bf16 at Wb+65536
            Wb[65536 + t] = f2b(t < 128 ? lnw[t] : lnb[t - 128]);
        }
        return;
    }
    // ---- transpose + LN stats: 288 blocks ----
    u16 (*X)[34] = (u16(*)[34])SH;   // [128][34]
    int b = blk / 72;
    int p0 = (blk % 72) * 32;
#pragma unroll 4
    for (int i = 0; i < 16; ++i) {
        int c = i * 8 + (t >> 5);
        int pix = t & 31;
        X[c][pix] = f2b(F[((size_t)(b * 128 + c)) * 2304 + p0 + pix]);
    }
    __syncthreads();
    int pix = t >> 3;
    int c0 = (t & 7) * 16;
    size_t row = (size_t)(b * 2304 + p0 + pix) * 128;
    float s = 0.f, s2 = 0.f;
#pragma unroll
    for (int sg = 0; sg < 2; ++sg) {
        v8s raw;
#pragma unroll
        for (int j = 0; j < 8; ++j) {
            u16 u = X[c0 + sg * 8 + j][pix];
            raw[j] = (short)u;
            float v = b2f(u);
            s += v; s2 += v * v;
        }
        *(v8s_am*)&Xt[row + c0 + sg * 8] = raw;
    }
    s += __shfl_xor(s, 1);  s2 += __shfl_xor(s2, 1);
    s += __shfl_xor(s, 2);  s2 += __shfl_xor(s2, 2);
    s += __shfl_xor(s, 4);  s2 += __shfl_xor(s2, 4);
    if ((t & 7) == 0) {
        float mean = s * (1.f / 128.f);
        float var = s2 * (1.f / 128.f) - mean * mean;
        float rstd = rsqrtf(var + 1e-5f);
        MuRs[(b * 2304 + p0 + pix) * 2]     = mean;
        MuRs[(b * 2304 + p0 + pix) * 2 + 1] = rstd;
    }
}

// ---------------------------------------------------------------------------
// Kernel 2: fused attention, 2 windows per block. 288 blocks x 512 thr
// (8 waves), wave w = head w for both windows. v12 staged-KB tile loop;
// per-tile K ds_reads and V loads are shared by the two windows.
// LDS: KB 34.8 KB + VtW 34.8 KB = 69.6 KB -> 2 blocks/CU.
__global__ __launch_bounds__(512, 4) void k_attn_fused(
    const float* __restrict__ F,
    const u16* __restrict__ Xt,
    const float* __restrict__ MuRs,
    const u16* __restrict__ KVg,
    const u16* __restrict__ VTg,
    const u16* __restrict__ Wb,     // [qwb|kvwb|owb|lnwb|lnbb]
    const float* __restrict__ qb,
    const float* __restrict__ kvb,
    const float* __restrict__ ob,
    float* __restrict__ Out)
{
    __shared__ u16 KB[2][64][136];      // pooled K tiles, double-buffered
    __shared__ u16 VtW[8][2][16][68];   // per-wave/window local V^T; At overlay

    const u16* qwb  = Wb;
    const u16* kvwb = Wb + 16384;
    const u16* owb  = Wb + 49152;
    const u16* lnwb = Wb + 65536;
    const u16* lnbb = Wb + 65664;
    u16* Atp = &VtW[0][0][0][0];        // overlay [2][16][136] = 4352 u16

    // Bijective XCD swizzle: 288 = 8 xcd x 36. xcd -> one batch-half.
    int blk = blockIdx.x;
    int xcd = blk & 7, jj = blk >> 3;   // jj 0..35
    int b = xcd >> 1;
    int wr = (xcd & 1) * 6 + jj / 6;
    int wcp = jj % 6;                   // window-pair; windows wc=2*wcp+{0,1}

    int t = threadIdx.x;
    int lane = t & 63, wave = t >> 6, n15 = lane & 15, quad = lane >> 4;
    v8s zf8 = {};
    v4f zz4 = {0.f, 0.f, 0.f, 0.f};
    const float QSCALE = 0.25f * 1.44269504f;

    // --- issue tile-0 pooled-K staging loads first ---
    v8s stg[2];
#pragma unroll
    for (int i = 0; i < 2; ++i) {
        int chunk = i * 512 + t;
        stg[i] = *(const v8s_am*)&KVg[((size_t)(b * 576 + (chunk >> 4))) * 128 + (chunk & 15) * 8];
    }

    // --- LN + Q projection per window: qf[wi] = Q^T fragment ---
    v4s qf[2];
#pragma unroll
    for (int wi = 0; wi < 2; ++wi) {
        int wc = wcp * 2 + wi;
        int qh = wr * 4 + (n15 >> 2), qw_ = wc * 4 + (n15 & 3);
        int qpix = b * 2304 + qh * 48 + qw_;
        float mu = MuRs[qpix * 2], rstd = MuRs[qpix * 2 + 1];
        v8s xln[4];
#pragma unroll
        for (int kc = 0; kc < 4; ++kc) {
            v8s x  = *(const v8s_am*)&Xt[(size_t)qpix * 128 + kc * 32 + quad * 8];
            v8s lw = *(const v8s_am*)&lnwb[kc * 32 + quad * 8];
            v8s lb = *(const v8s_am*)&lnbb[kc * 32 + quad * 8];
            v8s y;
#pragma unroll
            for (int j = 0; j < 8; ++j)
                y[j] = (short)f2b((b2f((u16)x[j]) - mu) * rstd * b2f((u16)lw[j]) + b2f((u16)lb[j]));
            xln[kc] = y;
        }
        int n0 = wave * 16;
        v4f qacc = zz4;
#pragma unroll
        for (int kc = 0; kc < 4; ++kc) {
            v8s aw = *(const v8s_am*)&qwb[((size_t)(n0 + n15)) * 128 + kc * 32 + quad * 8];
            qacc = MFMA_BF16(aw, xln[kc], qacc);
        }
        v4s q4;
#pragma unroll
        for (int r = 0; r < 4; ++r)
            q4[r] = (short)f2b((qacc[r] + qb[n0 + quad * 4 + r]) * QSCALE);
        qf[wi] = q4;
    }

    // --- local K/V projection per window (this wave's head only) ---
    v4s kfloc[2][4];
#pragma unroll
    for (int wi = 0; wi < 2; ++wi) {
        int wc = wcp * 2 + wi;
#pragma unroll
        for (int g = 0; g < 4; ++g) {
            int tl = g * 16 + n15;
            int fh = tl >> 3, fw = tl & 7;
            int hh = wr * 4 - 2 + fh, ww = wc * 4 - 2 + fw;
            bool valid = (hh >= 0 && hh < 48 && ww >= 0 && ww < 48);
            size_t arow = (size_t)(b * 2304 + hh * 48 + ww) * 128;
            v8s xb[4];
#pragma unroll
            for (int kc = 0; kc < 4; ++kc) {
                v8s v = zf8;
                if (valid) v = *(const v8s_am*)&Xt[arow + kc * 32 + quad * 8];
                xb[kc] = v;
            }
#pragma unroll
            for (int s = 0; s < 2; ++s) {    // s=0: K strip, s=1: V strip
                int sbase = s * 128 + wave * 16;
                v4f acc = zz4;
#pragma unroll
                for (int kc = 0; kc < 4; ++kc) {
                    v8s aw = *(const v8s_am*)&kvwb[((size_t)(sbase + n15)) * 128 + kc * 32 + quad * 8];
                    acc = MFMA_BF16(aw, xb[kc], acc);
                }
                if (s == 0) {
                    v4s k4;
#pragma unroll
                    for (int r = 0; r < 4; ++r)
                        k4[r] = (short)f2b(acc[r] + kvb[sbase + quad * 4 + r]);
                    kfloc[wi][g] = k4;
                } else {
#pragma unroll
                    for (int r = 0; r < 4; ++r)
                        VtW[wave][wi][quad * 4 + r][g * 16 + n15] =
                            f2b(acc[r] + kvb[sbase + quad * 4 + r]);
                }
            }
        }
    }

    v4f oacc[2] = {};
    float ls0 = 0.f, ls1 = 0.f;
    const u16* VTb = VTg + (size_t)b * 92160;

    // --- local chunk (K frags in regs, V from wave-private LDS slice) ---
    asm volatile("s_waitcnt lgkmcnt(0)" ::: "memory");
#pragma unroll
    for (int wi = 0; wi < 2; ++wi) {
#pragma unroll
        for (int g = 0; g < 4; ++g) {
            v4f St = MFMA16(kfloc[wi][g], qf[wi], zz4);  // S^T[tok][q=n15]
            float p0 = EXP2(St[0]), p1 = EXP2(St[1]);
            float p2 = EXP2(St[2]), p3 = EXP2(St[3]);
            if (wi == 0) ls0 += (p0 + p1) + (p2 + p3);
            else         ls1 += (p0 + p1) + (p2 + p3);
            v4s pk = {(short)f2b(p0), (short)f2b(p1), (short)f2b(p2), (short)f2b(p3)};
            v4s vf = *(const v4s_am*)&VtW[wave][wi][n15][g * 16 + quad * 4];
            oacc[wi] = MFMA16(vf, pk, oacc[wi]);         // O^T[ch][q=n15]
        }
    }

    // --- write tile 0 into KB[1] ---
#pragma unroll
    for (int i = 0; i < 2; ++i) {
        int chunk = i * 512 + t;
        *(v8s_am*)&KB[1][chunk >> 4][(chunk & 15) * 8] = stg[i];
    }
    __syncthreads();

    // --- pooled tiles 0..10; tile tb lives in KB[1-(tb&1)] ---
    for (int tb = 0; tb <= 10; ++tb) {
        v4s vp[4];
        {
            const u16* vrow = VTb + (size_t)(wave * 16 + n15) * 720 + tb * 64 + quad * 4;
#pragma unroll
            for (int g = 0; g < 4; ++g)
                vp[g] = *(const v4s_am*)(vrow + g * 16);
        }
        int nt_ = tb + 1;
        int rowbase = (nt_ < 9) ? (b * 576 + nt_ * 64)
                                : (2304 + b * 144 + nt_ * 64 - 576);
        int nrows = (nt_ == 11) ? 16 : 64;
        bool sv[2];
#pragma unroll
        for (int i = 0; i < 2; ++i) {
            int chunk = i * 512 + t;
            int rr = chunk >> 4;
            sv[i] = rr < nrows;
            if (sv[i])
                stg[i] = *(const v8s_am*)&KVg[((size_t)(rowbase + rr)) * 128 + (chunk & 15) * 8];
        }
        const u16 (*KBc)[136] = KB[1 - (tb & 1)];
#pragma unroll
        for (int g = 0; g < 4; ++g) {
            v4s kf = *(const v4s_am*)&KBc[g * 16 + n15][wave * 16 + quad * 4];
            v4f St0 = MFMA16(kf, qf[0], zz4);
            v4f St1 = MFMA16(kf, qf[1], zz4);
            float a0 = EXP2(St0[0]), a1 = EXP2(St0[1]), a2 = EXP2(St0[2]), a3 = EXP2(St0[3]);
            float b0 = EXP2(St1[0]), b1 = EXP2(St1[1]), b2 = EXP2(St1[2]), b3 = EXP2(St1[3]);
            ls0 += (a0 + a1) + (a2 + a3);
            ls1 += (b0 + b1) + (b2 + b3);
            v4s pk0 = {(short)f2b(a0), (short)f2b(a1), (short)f2b(a2), (short)f2b(a3)};
            v4s pk1 = {(short)f2b(b0), (short)f2b(b1), (short)f2b(b2), (short)f2b(b3)};
            oacc[0] = MFMA16(vp[g], pk0, oacc[0]);
            oacc[1] = MFMA16(vp[g], pk1, oacc[1]);
        }
#pragma unroll
        for (int i = 0; i < 2; ++i) {
            if (sv[i]) {
                int chunk = i * 512 + t;
                *(v8s_am*)&KB[tb & 1][chunk >> 4][(chunk & 15) * 8] = stg[i];
            }
        }
        __syncthreads();
    }
    // --- tile 11: 16 toks (glo 128..143), buffer KB[0] ---
    {
        v4s vf = *(const v4s_am*)(VTb + (size_t)(wave * 16 + n15) * 720 + 704 + quad * 4);
        v4s kf = *(const v4s_am*)&KB[0][n15][wave * 16 + quad * 4];
        v4f St0 = MFMA16(kf, qf[0], zz4);
        v4f St1 = MFMA16(kf, qf[1], zz4);
        float a0 = EXP2(St0[0]), a1 = EXP2(St0[1]), a2 = EXP2(St0[2]), a3 = EXP2(St0[3]);
        float b0 = EXP2(St1[0]), b1 = EXP2(St1[1]), b2 = EXP2(St1[2]), b3 = EXP2(St1[3]);
        ls0 += (a0 + a1) + (a2 + a3);
        ls1 += (b0 + b1) + (b2 + b3);
        v4s pk0 = {(short)f2b(a0), (short)f2b(a1), (short)f2b(a2), (short)f2b(a3)};
        v4s pk1 = {(short)f2b(b0), (short)f2b(b1), (short)f2b(b2), (short)f2b(b3)};
        oacc[0] = MFMA16(vf, pk0, oacc[0]);
        oacc[1] = MFMA16(vf, pk1, oacc[1]);
    }

    // --- l reduce; write attended into At (overlay on VtW: all VtW reads
    //     happened before barrier 1; writers passed 12 barriers since) ---
#pragma unroll
    for (int wi = 0; wi < 2; ++wi) {
        float ls = wi == 0 ? ls0 : ls1;
        ls += __shfl_xor(ls, 16);
        ls += __shfl_xor(ls, 32);
        float inv = 1.f / ls;
        v4s a4 = {(short)f2b(oacc[wi][0] * inv), (short)f2b(oacc[wi][1] * inv),
                  (short)f2b(oacc[wi][2] * inv), (short)f2b(oacc[wi][3] * inv)};
        *(v4s_am*)&Atp[wi * 2176 + n15 * 136 + wave * 16 + quad * 4] = a4;
    }
    __syncthreads();    // the only post-loop barrier

    // --- out projection (16 out-ch per wave) + bias + residual, NCHW ---
#pragma unroll
    for (int wi = 0; wi < 2; ++wi) {
        int wc = wcp * 2 + wi;
        int n0 = wave * 16;
        v4f oa = zz4;
#pragma unroll
        for (int kc = 0; kc < 4; ++kc) {
            v8s af = *(const v8s_am*)&Atp[wi * 2176 + n15 * 136 + kc * 32 + quad * 8];
            v8s bf = *(const v8s_am*)&owb[((size_t)(n0 + n15)) * 128 + kc * 32 + quad * 8];
            oa = MFMA_BF16(af, bf, oa);
        }
        int c = n0 + n15;
        float bv = ob[c];
#pragma unroll
        for (int r = 0; r < 4; ++r) {
            int pix = quad * 4 + r;
            int hh = wr * 4 + (pix >> 2), ww_ = wc * 4 + (pix & 3);
            size_t idx = ((size_t)(b * 128 + c)) * 2304 + hh * 48 + ww_;
            Out[idx] = oa[r] + bv + F[idx];
        }
    }
}

// ---------------------------------------------------------------------------
extern "C" void kernel_launch(void* const* d_in, const int* in_sizes, int n_in,
                              void* d_out, int out_size, void* d_ws, size_t ws_size,
                              hipStream_t stream)
{
    const float* F   = (const float*)d_in[0];
    const float* lnw = (const float*)d_in[1];
    const float* lnb = (const float*)d_in[2];
    const float* qw  = (const float*)d_in[3];
    const float* qb  = (const float*)d_in[4];
    const float* kvw = (const float*)d_in[5];
    const float* kvb = (const float*)d_in[6];
    const float* ow  = (const float*)d_in[7];
    const float* ob  = (const float*)d_in[8];
    float* Out = (float*)d_out;

    u16* ws    = (u16*)d_ws;
    u16* Xt    = ws;                    // 9216*128  = 1,179,648 u16
    u16* Pml   = Xt + 9216 * 128;       // (unused in v14; layout kept)
    u16* KVg   = Pml + 2880 * 128;      // 2880*128  =   368,640
    u16* VTg   = KVg + 2880 * 128;      // 4*128*720 =   368,640
    u16* Wb    = VTg + 4 * 128 * 720;   // 65,792 [qwb|kvwb|owb|lnwb|lnbb]
    float* MuRs = (float*)(Wb + 65792); // 9216*2 fp32
    // total: ~4.77 MiB

    k_prep_gemm<<<484, 256, 0, stream>>>(F, qw, kvw, ow, lnw, lnb, kvb,
                                         Xt, Wb, MuRs, KVg, VTg);
    k_attn_fused<<<288, 512, 0, stream>>>(F, Xt, MuRs, KVg, VTg, Wb,
                                          qb, kvb, ob, Out);
}